// Round 1
// baseline (318.942 us; speedup 1.0000x reference)
//
#include <hip/hip_runtime.h>

// EvolvedLoss: pure elementwise over 2^25 fp32 elements.
// loss = m8 + c7*m5 where
//   m2 = o - t; m3 = m2^2; m4 = tanh(c[2]*m2 + c2[2]);
//   m5 = m3 + c[3]*m4; m6 = exp(-c[4]*m3); m7 = m5*m6;
//   m8 = m7 / (1 + c[6]*m3)
// Memory-bound: 402.7 MB traffic -> ~64 us floor at 6.3 TB/s.

__device__ __forceinline__ float evolved_elem(float o, float t,
                                              float c2v, float c2b,
                                              float c3, float c4,
                                              float c6, float c7) {
    float m2 = o - t;
    float m3 = m2 * m2;
    float m4 = tanhf(fmaf(c2v, m2, c2b));
    float m5 = fmaf(c3, m4, m3);
    float m6 = expf(-c4 * m3);
    float m7 = m5 * m6;
    float m8 = m7 / fmaf(c6, m3, 1.0f);
    return fmaf(c7, m5, m8);
}

__global__ __launch_bounds__(256) void EvolvedLoss_kernel(
    const float* __restrict__ outs, const float* __restrict__ tgts,
    const float* __restrict__ c, const float* __restrict__ c2,
    float* __restrict__ loss, int n4, int n) {
    // Uniform scalar loads of the 6 constants used (L2-cached, once/wave).
    const float c2v = c[2];
    const float c3  = c[3];
    const float c4  = c[4];
    const float c6  = c[6];
    const float c7  = c[7];
    const float c2b = c2[2];

    const float4* o4 = reinterpret_cast<const float4*>(outs);
    const float4* t4 = reinterpret_cast<const float4*>(tgts);
    float4* l4 = reinterpret_cast<float4*>(loss);

    int idx = blockIdx.x * blockDim.x + threadIdx.x;
    int stride = gridDim.x * blockDim.x;

    for (int i = idx; i < n4; i += stride) {
        float4 o = o4[i];
        float4 t = t4[i];
        float4 r;
        r.x = evolved_elem(o.x, t.x, c2v, c2b, c3, c4, c6, c7);
        r.y = evolved_elem(o.y, t.y, c2v, c2b, c3, c4, c6, c7);
        r.z = evolved_elem(o.z, t.z, c2v, c2b, c3, c4, c6, c7);
        r.w = evolved_elem(o.w, t.w, c2v, c2b, c3, c4, c6, c7);
        l4[i] = r;
    }

    // Tail (n not divisible by 4): handled by first threads of the grid.
    int tail_start = n4 * 4;
    int tail_i = tail_start + idx;
    if (tail_i < n) {
        loss[tail_i] = evolved_elem(outs[tail_i], tgts[tail_i],
                                    c2v, c2b, c3, c4, c6, c7);
    }
}

extern "C" void kernel_launch(void* const* d_in, const int* in_sizes, int n_in,
                              void* d_out, int out_size, void* d_ws, size_t ws_size,
                              hipStream_t stream) {
    const float* outs = (const float*)d_in[0];
    const float* tgts = (const float*)d_in[1];
    const float* c    = (const float*)d_in[2];
    const float* c2   = (const float*)d_in[3];
    float* loss = (float*)d_out;

    int n  = in_sizes[0];      // 4096*8192 = 33,554,432
    int n4 = n / 4;            // 8,388,608 float4 elements

    const int block = 256;
    int grid = (n4 + block - 1) / block;
    if (grid > 2048) grid = 2048;   // ~8 blocks/CU, grid-stride the rest

    EvolvedLoss_kernel<<<grid, block, 0, stream>>>(outs, tgts, c, c2,
                                                   loss, n4, n);
}